// Round 1
// 2045.010 us; speedup vs baseline: 1.2068x; 1.2068x over previous
//
#include <hip/hip_runtime.h>
#include <math.h>

#define NN 50000
#define TT 12
#define EE 1600000
#define FF 16
#define HH 128
#define CHK 4096     // edges per chunk (level-1 histogram / scatter staging)
#define NCH 391      // ceil(EE/CHK)
#define BKT 128      // nodes per bin
#define NBINS 391    // ceil(NN/BKT) -> covers 50048
#define CAP 6144     // max edges per bin segment (mean 4096, sigma 64)
#define RP 50016     // rowptr stride per t (>= NN+1)
#define CGB 782      // ceil(NN/64) cell blocks
#define AH_STR 136   // h-part A LDS stride (halves): 272B rows, 2-way-free banking
#define AX_STR 40    // x-part A LDS stride (halves)
#define HC_STR 136   // committed-h LDS stride (halves)
#define BKROW 160    // BcatT row stride in halves: [h 0..127 | x 128..143 | zero 144..159]

typedef _Float16 half8_t __attribute__((ext_vector_type(8)));
typedef float floatx4 __attribute__((ext_vector_type(4)));

__device__ __forceinline__ float h16_to_f(unsigned short u) {
    _Float16 h; __builtin_memcpy(&h, &u, 2); return (float)h;
}
__device__ __forceinline__ unsigned short f_to_h16(float f) {
    _Float16 h = (_Float16)f; unsigned short u; __builtin_memcpy(&u, &h, 2); return u;
}
__device__ __forceinline__ float fsig(float x) {
    return 1.0f / (1.0f + exp2f(-1.44269504f * x));
}
__device__ __forceinline__ float ftanh(float x) {
    return 2.0f / (1.0f + exp2f(-2.88539009f * x)) - 1.0f;
}

// ---------------------------------------------------------------------------
// P0: detect mask dtype from byte pattern (uint8 / int32 / float32).
__global__ void detect_mask(const unsigned char* __restrict__ m, int* __restrict__ flag) {
    __shared__ int cnt[2];
    if (threadIdx.x < 2) cnt[threadIdx.x] = 0;
    __syncthreads();
    int a = 0, b = 0;
    for (int base = 0; base < 4096; base += 256) {
        int idx = base + threadIdx.x;
        unsigned char v = m[idx];
        int r = idx & 3;
        if (v) { if (r == 0) a++; else if (r == 1) b++; }
    }
    atomicAdd(&cnt[0], a);
    atomicAdd(&cnt[1], b);
    __syncthreads();
    if (threadIdx.x == 0) flag[0] = cnt[1] > 0 ? 0 : (cnt[0] > 0 ? 1 : 2);
}

// P1: hm[t][n] = mask & seen-before, mc[t][n] = mask
__global__ void build_masks(const void* __restrict__ mask, const int* __restrict__ flag,
                            unsigned char* __restrict__ hm, unsigned char* __restrict__ mc) {
    int n = blockIdx.x * 256 + threadIdx.x;
    if (n >= NN) return;
    int mode = flag[0];
    bool seen = false;
    for (int t = 0; t < TT; t++) {
        int idx = t * NN + n;
        bool m;
        if (mode == 0)      m = ((const unsigned char*)mask)[idx] != 0;
        else if (mode == 1) m = ((const int*)mask)[idx] != 0;
        else                m = ((const float*)mask)[idx] != 0.0f;
        hm[idx] = (m && seen) ? 1 : 0;
        mc[idx] = m ? 1 : 0;
        seen = seen || m;
    }
}

// ---------------------------------------------------------------------------
// S1: per-chunk histogram of dst bins (bin = dst>>7). layout [t][bin][chunk]
__global__ void hist_kernel(const int* __restrict__ ei, int* __restrict__ chunkHist) {
    __shared__ int h[NBINS + 1];
    int c = blockIdx.x, t = blockIdx.y, tid = threadIdx.x;
    for (int i = tid; i < NBINS; i += 256) h[i] = 0;
    __syncthreads();
    const int* dstp = ei + (size_t)(2 * t + 1) * EE;
    int e0 = c * CHK;
    for (int i = tid; i < CHK; i += 256) {
        int e = e0 + i;
        if (e < EE) atomicAdd(&h[dstp[e] >> 7], 1);
    }
    __syncthreads();
    for (int i = tid; i < NBINS; i += 256)
        chunkHist[((size_t)t * NBINS + i) * NCH + c] = h[i];
}

// S2: in-place exclusive scan of each t's [NBINS*NCH] array
__global__ void scan_kernel(int* __restrict__ buf) {
    __shared__ int ps[1024];
    const int L = NBINS * NCH;   // 152881
    const int PER = 150;         // 1024*150 >= L
    int t = blockIdx.x, tid = threadIdx.x;
    int* a = buf + (size_t)t * L;
    int i0 = tid * PER, i1 = min(i0 + PER, L);
    int s = 0;
    for (int i = i0; i < i1; i++) s += a[i];
    ps[tid] = s;
    __syncthreads();
    for (int off = 1; off < 1024; off <<= 1) {
        int v = (tid >= off) ? ps[tid - off] : 0;
        __syncthreads();
        ps[tid] += v;
        __syncthreads();
    }
    int base = (tid == 0) ? 0 : ps[tid - 1];
    for (int i = i0; i < i1; i++) { int v = a[i]; a[i] = base; base += v; }
}

// S3: LDS-staged scatter into bin-sorted order (batch of 6 t's).
// Record: uint2{src|dst<<16, w_f32}. Coalesced segment write-out.
__launch_bounds__(256)
__global__ void scatter_kernel(const int* __restrict__ ei, const float* __restrict__ ea,
                               const int* __restrict__ chunkOff, uint2* __restrict__ E2,
                               int batch) {
    __shared__ uint2 sorted[CHK];          // 32 KB
    __shared__ int cnt[NBINS];
    __shared__ int sA[NBINS], sB[NBINS];
    __shared__ int start[NBINS], gbase[NBINS];
    int c = blockIdx.x, y = blockIdx.y, tid = threadIdx.x;
    int t = batch * 6 + y;
    for (int i = tid; i < NBINS; i += 256) {
        cnt[i] = 0;
        gbase[i] = chunkOff[((size_t)t * NBINS + i) * NCH + c];
    }
    __syncthreads();
    const int* srcp = ei + (size_t)(2 * t) * EE;
    const int* dstp = ei + (size_t)(2 * t + 1) * EE;
    const float* wp = ea + (size_t)t * EE;
    int e0 = c * CHK;
    int m = min(CHK, EE - e0);
    uint2 rec[16];
    int rank[16];
#pragma unroll
    for (int k = 0; k < 16; k++) {
        int i = k * 256 + tid;
        rank[k] = -1;
        if (i < m) {
            int e = e0 + i;
            unsigned int s = (unsigned int)srcp[e];
            unsigned int d = (unsigned int)dstp[e];
            float wv = wp[e];
            rec[k].x = s | (d << 16);
            rec[k].y = __float_as_uint(wv);
            rank[k] = atomicAdd(&cnt[d >> 7], 1);
        }
    }
    __syncthreads();
    for (int i = tid; i < NBINS; i += 256) sA[i] = cnt[i];
    __syncthreads();
    int pp = 0;
    for (int off = 1; off < NBINS; off <<= 1) {
        if (pp == 0) {
            for (int i = tid; i < NBINS; i += 256)
                sB[i] = (i >= off) ? sA[i] + sA[i - off] : sA[i];
        } else {
            for (int i = tid; i < NBINS; i += 256)
                sA[i] = (i >= off) ? sB[i] + sB[i - off] : sB[i];
        }
        pp ^= 1;
        __syncthreads();
    }
    const int* inc = pp ? sB : sA;
    for (int i = tid; i < NBINS; i += 256) start[i] = inc[i] - cnt[i];
    __syncthreads();
#pragma unroll
    for (int k = 0; k < 16; k++) {
        if (rank[k] >= 0) {
            int b = rec[k].x >> 23;
            sorted[start[b] + rank[k]] = rec[k];
        }
    }
    __syncthreads();
    uint2* outp = E2 + (size_t)y * EE;
    for (int i = tid; i < m; i += 256) {
        uint2 r = sorted[i];
        int b = r.x >> 23;
        outp[gbase[b] + (i - start[b])] = r;
    }
}

// S4: per-bin counting sort -> compact CSR records (src u16 | w'=w*dinv[d] f16)
// + rowptr + dinv. Reads uint2 staging E2, writes 4B records to E1.
__launch_bounds__(256)
__global__ void sortbin_kernel(const uint2* __restrict__ E2, const int* __restrict__ chunkHist,
                               unsigned int* __restrict__ E1, int* __restrict__ rowptr,
                               float* __restrict__ dinvG, int batch) {
    __shared__ uint2 es[CAP];   // 48 KB
    __shared__ int cnt[BKT];
    __shared__ float wsm[BKT];
    __shared__ int cur[BKT];
    int b = blockIdx.x, y = blockIdx.y, tid = threadIdx.x;
    int t = batch * 6 + y;
    const uint2* gE = E2 + (size_t)y * EE;
    unsigned int* oE = E1 + (size_t)t * EE;
    const int* off = chunkHist + (size_t)t * NBINS * NCH;
    int e0 = off[b * NCH];
    int e1 = (b == NBINS - 1) ? EE : off[(b + 1) * NCH];
    int seg = e1 - e0;
    for (int i = tid; i < seg; i += 256) es[i] = gE[e0 + i];
    if (tid < BKT) { cnt[tid] = 0; wsm[tid] = 0.0f; }
    __syncthreads();
    for (int i = tid; i < seg; i += 256) {
        int dl = (es[i].x >> 16) & 127;
        atomicAdd(&cnt[dl], 1);
        atomicAdd(&wsm[dl], __uint_as_float(es[i].y));
    }
    __syncthreads();
    int ogv = (tid < BKT) ? cnt[tid] : 0;
    for (int o = 1; o < BKT; o <<= 1) {
        int u = (tid < BKT && tid >= o) ? cnt[tid - o] : 0;
        __syncthreads();
        if (tid < BKT) cnt[tid] += u;
        __syncthreads();
    }
    if (tid < BKT) {
        int exc = cnt[tid] - ogv;
        cur[tid] = exc;
        float dv = rsqrtf(1.0f + wsm[tid]);
        wsm[tid] = dv;   // reuse as dinv-local
        int node = b * BKT + tid;
        if (node <= NN) {
            rowptr[(size_t)t * RP + node] = e0 + exc;
            if (node < NN) dinvG[(size_t)t * NN + node] = dv;
        }
    }
    __syncthreads();
    for (int i = tid; i < seg; i += 256) {
        uint2 p = es[i];
        int dl = (p.x >> 16) & 127;
        int pos = atomicAdd(&cur[dl], 1);
        float wv = __uint_as_float(p.y) * wsm[dl];
        oE[e0 + pos] = (p.x & 0xFFFF) | ((unsigned int)f_to_h16(wv) << 16);
    }
}

// S4b: xs[t][n][f] = (f16)(dinv[t][n] * x[t][n][f])
__global__ void xs_kernel(const float* __restrict__ x, const float* __restrict__ dinvG,
                          _Float16* __restrict__ xs16) {
    int gid = blockIdx.x * 256 + threadIdx.x;   // TT*NN*4 float4 groups (exact: 9375 blocks)
    int tn = gid >> 2;
    float dd = dinvG[tn];
    float4 v = ((const float4*)x)[gid];
    _Float16 h[4] = {(_Float16)(dd * v.x), (_Float16)(dd * v.y),
                     (_Float16)(dd * v.z), (_Float16)(dd * v.w)};
    uint2 o;
    __builtin_memcpy(&o, h, 8);
    ((uint2*)xs16)[gid] = o;
}

// S5: CSR gather: wave per (t,node). 8 edges x 8 feature-pairs per iteration.
// xagg[t][n][f] = sum_e w'_e * xs[s][f] + dinv[n]*xs[n][f]   (all f16 in, f32 acc)
__global__ void gather_csr(const unsigned int* __restrict__ E1, const int* __restrict__ rowptr,
                           const float* __restrict__ dinvG, const _Float16* __restrict__ xs16,
                           _Float16* __restrict__ xagg16) {
    int t = blockIdx.y;
    int n = blockIdx.x * 4 + (threadIdx.x >> 6);
    if (n >= NN) return;
    int lane = threadIdx.x & 63;
    int eo = lane >> 3, fp = lane & 7;
    const unsigned int* gE = E1 + (size_t)t * EE;
    const _Float16* xs = xs16 + (size_t)t * NN * FF;
    int r0 = rowptr[(size_t)t * RP + n], r1 = rowptr[(size_t)t * RP + n + 1];
    float a0 = 0.0f, a1 = 0.0f;
    for (int e = r0 + eo; e < r1; e += 8) {
        unsigned int rec = gE[e];
        float wv = h16_to_f((unsigned short)(rec >> 16));
        unsigned int xp = *(const unsigned int*)(xs + (size_t)(rec & 0xFFFF) * FF + 2 * fp);
        a0 += wv * h16_to_f((unsigned short)(xp & 0xFFFF));
        a1 += wv * h16_to_f((unsigned short)(xp >> 16));
    }
    a0 += __shfl_xor(a0, 8);  a1 += __shfl_xor(a1, 8);
    a0 += __shfl_xor(a0, 16); a1 += __shfl_xor(a1, 16);
    a0 += __shfl_xor(a0, 32); a1 += __shfl_xor(a1, 32);
    if (eo == 0) {
        float dd = dinvG[(size_t)t * NN + n];
        unsigned int xp = *(const unsigned int*)(xs + (size_t)n * FF + 2 * fp);
        float o0 = a0 + dd * h16_to_f((unsigned short)(xp & 0xFFFF));
        float o1 = a1 + dd * h16_to_f((unsigned short)(xp >> 16));
        unsigned int pack = (unsigned int)f_to_h16(o0) | ((unsigned int)f_to_h16(o1) << 16);
        ((unsigned int*)(xagg16 + ((size_t)t * NN + n) * FF))[fp] = pack;
    }
}

// S6 (horizon): 3-feature CSR re-aggregation of predsc (= dinv*pred) over t=11.
__global__ void gather3_csr(const unsigned int* __restrict__ E1, const int* __restrict__ rowptr,
                            const float* __restrict__ dinvG, const float* __restrict__ predsc,
                            _Float16* __restrict__ xaggH16) {
    int n = blockIdx.x * 4 + (threadIdx.x >> 6);
    if (n >= NN) return;
    int lane = threadIdx.x & 63;
    int eo = lane >> 2, f = lane & 3;
    const unsigned int* gE = E1 + (size_t)11 * EE;
    const float* dv = dinvG + (size_t)11 * NN;
    int r0 = rowptr[(size_t)11 * RP + n], r1 = rowptr[(size_t)11 * RP + n + 1];
    float acc = 0.0f;
    for (int e = r0 + eo; e < r1; e += 16) {
        unsigned int rec = gE[e];
        float wv = h16_to_f((unsigned short)(rec >> 16));
        if (f < 3) acc += wv * predsc[(size_t)(rec & 0xFFFF) * 4 + f];
    }
    acc += __shfl_xor(acc, 4);
    acc += __shfl_xor(acc, 8);
    acc += __shfl_xor(acc, 16);
    acc += __shfl_xor(acc, 32);
    if (lane < 3) {
        float res = acc + dv[n] * predsc[(size_t)n * 4 + f];
        xaggH16[(size_t)n * FF + f] = (_Float16)res;
    }
}

// ---------------------------------------------------------------------------
// W: fold Wc into Wl_top -> BcatT[g][n=128][k: h(0..127) | x(128..143) | 0(144..159)]
// (K reordered so MFMA ks0..3 hit the pure-h part and ks4 the x part + zero pad)
__global__ void weight_kernel(const float* Wc0, const float* bc0, const float* Wl0, const float* bl0,
                              const float* Wc1, const float* bc1, const float* Wl1, const float* bl1,
                              const float* Wc2, const float* bc2, const float* Wl2, const float* bl2,
                              _Float16* __restrict__ BcatT, float* __restrict__ beff) {
    __shared__ float WcS[FF][HH];
    int g = blockIdx.x;
    int n = threadIdx.x;  // 128
    const float* Wc = g == 0 ? Wc0 : (g == 1 ? Wc1 : Wc2);
    const float* bc = g == 0 ? bc0 : (g == 1 ? bc1 : bc2);
    const float* Wl = g == 0 ? Wl0 : (g == 1 ? Wl1 : Wl2);
    const float* bl = g == 0 ? bl0 : (g == 1 ? bl1 : bl2);
    for (int q = 0; q < FF; q++) WcS[q][n] = Wc[q * HH + n];
    __syncthreads();
    float acc[FF];
#pragma unroll
    for (int i = 0; i < FF; i++) acc[i] = 0.0f;
    float accb = 0.0f;
    for (int k = 0; k < HH; k++) {
        float wl = Wl[k * HH + n];
        accb += bc[k] * wl;
#pragma unroll
        for (int i = 0; i < FF; i++) acc[i] += WcS[i][k] * wl;
    }
    _Float16* row = BcatT + ((size_t)g * HH + n) * BKROW;
    for (int j = 0; j < HH; j++) row[j] = (_Float16)Wl[(size_t)(HH + j) * HH + n];
#pragma unroll
    for (int i = 0; i < FF; i++) row[HH + i] = (_Float16)acc[i];
#pragma unroll
    for (int i = 144; i < 160; i++) row[i] = (_Float16)0.0f;
    beff[g * HH + n] = bl[n] + accb;
}

// ---------------------------------------------------------------------------
// CELLSEQ: fused multi-step GRU cell. Recurrence is per-node (GCN mixes x only),
// so each block keeps its 64 rows' committed h resident in LDS across all nt steps.
// 4 waves x 32 output-cols each; z/r B-fragments persistent in registers
// (loaded once per block); h~ B streamed from L2 per step. 4 barriers/step.
// rec mode (hm/mc != null): Hc starts 0, loop TT steps with masks, final write
//   hio = mc[last] ? Hc : 0   (== old prep_hp output).
// single mode: Ah <- hio (global), one step, h_new -> hio in place.
__launch_bounds__(256, 2)
__global__ void cellseq_kernel(const _Float16* __restrict__ xaggBase,
                               _Float16* __restrict__ hio,
                               const _Float16* __restrict__ BcatT,
                               const float* __restrict__ beff,
                               const unsigned char* __restrict__ hmAll,
                               const unsigned char* __restrict__ mcAll,
                               int nt) {
    __shared__ _Float16 Ah[64 * AH_STR];   // 17408 B : h-part of A (k'=0..127)
    __shared__ _Float16 Ax[64 * AX_STR];   //  5120 B : x-part of A (k'=128..159)
    __shared__ _Float16 Hc[64 * HC_STR];   // 17408 B : committed h
    const int tid = threadIdx.x;
    const int m0 = blockIdx.x * 64;
    const int lane = tid & 63;
    const int w = tid >> 6;
    const int mrow = lane & 15;
    const int quad = lane >> 4;
    const int c0 = w * 32;
    const bool rec = (hmAll != nullptr);

    // persistent B fragments for gates z and r (one 32-col slice per wave)
    half8_t bz[2][5], br[2][5];
#pragma unroll
    for (int c = 0; c < 2; c++) {
        int col = c0 + c * 16 + mrow;
#pragma unroll
        for (int ks = 0; ks < 5; ks++) {
            bz[c][ks] = *(const half8_t*)(BcatT + (size_t)col * BKROW + ks * 32 + quad * 8);
            br[c][ks] = *(const half8_t*)(BcatT + (size_t)(HH + col) * BKROW + ks * 32 + quad * 8);
        }
    }
    float bzv[2], brv[2], bhv[2];
#pragma unroll
    for (int c = 0; c < 2; c++) {
        int col = c0 + c * 16 + mrow;
        bzv[c] = beff[col];
        brv[c] = beff[HH + col];
        bhv[c] = beff[2 * HH + col];
    }

    // zero Ax pad (k' 144..159, never rewritten) + init Hc = 0 in rec mode
    for (int idx = tid; idx < 128; idx += 256) {
        int row = idx >> 1, q = idx & 1;
        *(uint4*)(Ax + row * AX_STR + 16 + q * 8) = make_uint4(0, 0, 0, 0);
    }
    if (rec) {
        for (int idx = tid; idx < 1024; idx += 256) {
            int row = idx >> 4, q = idx & 15;
            *(uint4*)(Hc + row * HC_STR + q * 8) = make_uint4(0, 0, 0, 0);
        }
    }
    __syncthreads();

    for (int t = 0; t < nt; t++) {
        const _Float16* xa = xaggBase + (size_t)t * NN * FF;
        const unsigned char* hm = rec ? (hmAll + (size_t)t * NN) : nullptr;
        // ---- build A: Ah = (hm ? Hc : 0)  |  global h-in (single mode) ----
        for (int idx = tid; idx < 1024; idx += 256) {
            int row = idx >> 4, q = idx & 15;
            int g = m0 + row;
            uint4 v = make_uint4(0, 0, 0, 0);
            if (rec) {
                if (g < NN && hm[g]) v = *(const uint4*)(Hc + row * HC_STR + q * 8);
            } else {
                if (g < NN) v = *(const uint4*)(hio + (size_t)g * HH + q * 8);
            }
            *(uint4*)(Ah + row * AH_STR + q * 8) = v;
        }
        for (int idx = tid; idx < 128; idx += 256) {
            int row = idx >> 1, q = idx & 1;
            int g = m0 + row;
            uint4 v = make_uint4(0, 0, 0, 0);
            if (g < NN) v = *(const uint4*)(xa + (size_t)g * FF + q * 8);
            *(uint4*)(Ax + row * AX_STR + q * 8) = v;
        }
        __syncthreads();

        // ---- z and r MFMAs over all 64 rows (wave's 32 cols) ----
        floatx4 zacc[4][2], racc[4][2];
#pragma unroll
        for (int m = 0; m < 4; m++)
#pragma unroll
            for (int c = 0; c < 2; c++)
#pragma unroll
                for (int i = 0; i < 4; i++) { zacc[m][c][i] = 0.0f; racc[m][c][i] = 0.0f; }
#pragma unroll
        for (int m = 0; m < 4; m++) {
            half8_t a[5];
#pragma unroll
            for (int ks = 0; ks < 4; ks++)
                a[ks] = *(const half8_t*)(Ah + (m * 16 + mrow) * AH_STR + ks * 32 + quad * 8);
            a[4] = *(const half8_t*)(Ax + (m * 16 + mrow) * AX_STR + quad * 8);
#pragma unroll
            for (int c = 0; c < 2; c++) {
#pragma unroll
                for (int ks = 0; ks < 5; ks++)
                    zacc[m][c] = __builtin_amdgcn_mfma_f32_16x16x32_f16(a[ks], bz[c][ks], zacc[m][c], 0, 0, 0);
#pragma unroll
                for (int ks = 0; ks < 5; ks++)
                    racc[m][c] = __builtin_amdgcn_mfma_f32_16x16x32_f16(a[ks], br[c][ks], racc[m][c], 0, 0, 0);
            }
        }
        // hprev (pre-rescale) for the blend, from this wave's cols
        _Float16 hprev[32];
#pragma unroll
        for (int m = 0; m < 4; m++)
#pragma unroll
            for (int c = 0; c < 2; c++)
#pragma unroll
                for (int i = 0; i < 4; i++)
                    hprev[(m * 2 + c) * 4 + i] =
                        Ah[(m * 16 + quad * 4 + i) * AH_STR + c0 + c * 16 + mrow];
        __syncthreads();   // all waves done reading Ah

        // ---- stream h~ B-frags (L2-hot; latency hides under rescale VALU) ----
        half8_t bh[2][5];
#pragma unroll
        for (int c = 0; c < 2; c++) {
            int col = c0 + c * 16 + mrow;
#pragma unroll
            for (int ks = 0; ks < 5; ks++)
                bh[c][ks] = *(const half8_t*)(BcatT + (size_t)(2 * HH + col) * BKROW + ks * 32 + quad * 8);
        }
        // ---- rescale Ah in place: h-part *= sigmoid(r) (own cols only) ----
#pragma unroll
        for (int m = 0; m < 4; m++)
#pragma unroll
            for (int c = 0; c < 2; c++)
#pragma unroll
                for (int i = 0; i < 4; i++) {
                    int row = m * 16 + quad * 4 + i;
                    float rv = fsig(racc[m][c][i] + brv[c]);
                    Ah[row * AH_STR + c0 + c * 16 + mrow] =
                        (_Float16)((float)hprev[(m * 2 + c) * 4 + i] * rv);
                }
        __syncthreads();

        // ---- h~ MFMAs (Ah now h*r; Ax unchanged) ----
        floatx4 hacc[4][2];
#pragma unroll
        for (int m = 0; m < 4; m++)
#pragma unroll
            for (int c = 0; c < 2; c++)
#pragma unroll
                for (int i = 0; i < 4; i++) hacc[m][c][i] = 0.0f;
#pragma unroll
        for (int m = 0; m < 4; m++) {
            half8_t a[5];
#pragma unroll
            for (int ks = 0; ks < 4; ks++)
                a[ks] = *(const half8_t*)(Ah + (m * 16 + mrow) * AH_STR + ks * 32 + quad * 8);
            a[4] = *(const half8_t*)(Ax + (m * 16 + mrow) * AX_STR + quad * 8);
#pragma unroll
            for (int c = 0; c < 2; c++)
#pragma unroll
                for (int ks = 0; ks < 5; ks++)
                    hacc[m][c] = __builtin_amdgcn_mfma_f32_16x16x32_f16(a[ks], bh[c][ks], hacc[m][c], 0, 0, 0);
        }
        // ---- epilogue: h_new = z*h_prev + (1-z)*tanh(h~) ----
        const unsigned char* mc = rec ? (mcAll + (size_t)t * NN) : nullptr;
#pragma unroll
        for (int m = 0; m < 4; m++)
#pragma unroll
            for (int c = 0; c < 2; c++)
#pragma unroll
                for (int i = 0; i < 4; i++) {
                    int row = m * 16 + quad * 4 + i;
                    int g = m0 + row;
                    if (g < NN) {
                        int col = c0 + c * 16 + mrow;
                        float z = fsig(zacc[m][c][i] + bzv[c]);
                        float ht = ftanh(hacc[m][c][i] + bhv[c]);
                        float hp = (float)hprev[(m * 2 + c) * 4 + i];
                        float hn = z * hp + (1.0f - z) * ht;
                        if (rec) {
                            if (mc[g]) Hc[row * HC_STR + col] = (_Float16)hn;
                        } else {
                            hio[(size_t)g * HH + col] = (_Float16)hn;
                        }
                    }
                }
        __syncthreads();   // Hc commits / Ah readers done before next build
    }

    if (rec) {
        // final: hio = mc[last] ? Hc : 0   (fused prep_hp)
        const unsigned char* mcL = mcAll + (size_t)(nt - 1) * NN;
        for (int idx = tid; idx < 1024; idx += 256) {
            int row = idx >> 4, q = idx & 15;
            int g = m0 + row;
            if (g < NN) {
                uint4 v = make_uint4(0, 0, 0, 0);
                if (mcL[g]) v = *(const uint4*)(Hc + row * HC_STR + q * 8);
                *(uint4*)(hio + (size_t)g * HH + q * 8) = v;
            }
        }
    }
}

// C4: out[n][o] = h . head_W[:,o] + head_b[o]; also predsc[n][o] = dinv11[n]*out
__global__ void head_kernel(const _Float16* __restrict__ hp, const float* __restrict__ headW,
                            const float* __restrict__ headb, const float* __restrict__ dinv11,
                            float* __restrict__ out, float* __restrict__ predsc) {
    int node = (blockIdx.x * 256 + threadIdx.x) >> 6;
    int lane = threadIdx.x & 63;
    if (node >= NN) return;
    const _Float16* h = hp + (size_t)node * HH;
    float h0 = (float)h[lane], h1 = (float)h[64 + lane];
    float s0 = h0 * headW[lane * 3 + 0] + h1 * headW[(64 + lane) * 3 + 0];
    float s1 = h0 * headW[lane * 3 + 1] + h1 * headW[(64 + lane) * 3 + 1];
    float s2 = h0 * headW[lane * 3 + 2] + h1 * headW[(64 + lane) * 3 + 2];
#pragma unroll
    for (int off = 32; off > 0; off >>= 1) {
        s0 += __shfl_down(s0, off);
        s1 += __shfl_down(s1, off);
        s2 += __shfl_down(s2, off);
    }
    if (lane == 0) {
        float o0 = s0 + headb[0], o1 = s1 + headb[1], o2 = s2 + headb[2];
        out[(size_t)node * 3 + 0] = o0;
        out[(size_t)node * 3 + 1] = o1;
        out[(size_t)node * 3 + 2] = o2;
        float dd = dinv11[node];
        predsc[(size_t)node * 4 + 0] = dd * o0;
        predsc[(size_t)node * 4 + 1] = dd * o1;
        predsc[(size_t)node * 4 + 2] = dd * o2;
    }
}

extern "C" void kernel_launch(void* const* d_in, const int* in_sizes, int n_in,
                              void* d_out, int out_size, void* d_ws, size_t ws_size,
                              hipStream_t stream) {
    const float* x = (const float*)d_in[0];
    const int* ei = (const int*)d_in[1];
    const float* ea = (const float*)d_in[2];
    const void* mask = d_in[3];
    const float* Wc[3] = {(const float*)d_in[4], (const float*)d_in[8], (const float*)d_in[12]};
    const float* bc[3] = {(const float*)d_in[5], (const float*)d_in[9], (const float*)d_in[13]};
    const float* Wl[3] = {(const float*)d_in[6], (const float*)d_in[10], (const float*)d_in[14]};
    const float* bl[3] = {(const float*)d_in[7], (const float*)d_in[11], (const float*)d_in[15]};
    const float* headW = (const float*)d_in[16];
    const float* headb = (const float*)d_in[17];
    float* out = (float*)d_out;

    char* w = (char*)d_ws;
    auto alloc = [&](size_t bytes) {
        char* p = w;
        w += (bytes + 255) & ~(size_t)255;
        return p;
    };
    float* dinv = (float*)alloc((size_t)TT * NN * 4);
    _Float16* xagg16 = (_Float16*)alloc((size_t)TT * NN * FF * 2);
    _Float16* xaggH16 = (_Float16*)alloc((size_t)NN * FF * 2);
    _Float16* xs16 = (_Float16*)alloc((size_t)TT * NN * FF * 2);
    int* chunkHist = (int*)alloc((size_t)TT * NBINS * NCH * 4);
    int* rowptr = (int*)alloc((size_t)TT * RP * 4);
    unsigned int* E1 = (unsigned int*)alloc((size_t)TT * EE * 4);  // compact CSR records
    uint2* E2 = (uint2*)alloc((size_t)6 * EE * 8);                 // staging, 6 slots (2 batches)
    _Float16* BcatT = (_Float16*)alloc((size_t)3 * HH * BKROW * 2);
    float* beff = (float*)alloc(3 * HH * 4);
    float* predsc = (float*)alloc((size_t)NN * 4 * 4);
    unsigned char* hm = (unsigned char*)alloc((size_t)TT * NN);
    unsigned char* mc = (unsigned char*)alloc((size_t)TT * NN);
    int* flag = (int*)alloc(64);

    // f16 horizon hidden state aliases the E2 staging area (dead after sortbin).
    _Float16* hph = (_Float16*)E2;   // 12.8 MB

    detect_mask<<<1, 256, 0, stream>>>((const unsigned char*)mask, flag);
    build_masks<<<(NN + 255) / 256, 256, 0, stream>>>(mask, flag, hm, mc);

    hist_kernel<<<dim3(NCH, TT), 256, 0, stream>>>(ei, chunkHist);
    scan_kernel<<<TT, 1024, 0, stream>>>(chunkHist);
    for (int b = 0; b < 2; b++) {
        scatter_kernel<<<dim3(NCH, 6), 256, 0, stream>>>(ei, ea, chunkHist, E2, b);
        sortbin_kernel<<<dim3(NBINS, 6), 256, 0, stream>>>(E2, chunkHist, E1, rowptr, dinv, b);
    }
    xs_kernel<<<TT * NN * 4 / 256, 256, 0, stream>>>(x, dinv, xs16);
    gather_csr<<<dim3((NN + 3) / 4, TT), 256, 0, stream>>>(E1, rowptr, dinv, xs16, xagg16);

    weight_kernel<<<3, 128, 0, stream>>>(Wc[0], bc[0], Wl[0], bl[0],
                                         Wc[1], bc[1], Wl[1], bl[1],
                                         Wc[2], bc[2], Wl[2], bl[2], BcatT, beff);

    // fused recurrent chain t=0..11: h resident in LDS, writes hph = mc11 ? h : 0
    cellseq_kernel<<<CGB, 256, 0, stream>>>(xagg16, hph, BcatT, beff, hm, mc, TT);

    hipMemcpyAsync(xaggH16, xagg16 + (size_t)11 * NN * FF, (size_t)NN * FF * 2,
                   hipMemcpyDeviceToDevice, stream);

    for (int k = 0; k < 6; k++) {
        const _Float16* xa = (k == 0) ? (xagg16 + (size_t)11 * NN * FF) : xaggH16;
        cellseq_kernel<<<CGB, 256, 0, stream>>>(xa, hph, BcatT, beff, nullptr, nullptr, 1);
        head_kernel<<<NN * 64 / 256, 256, 0, stream>>>(hph, headW, headb, dinv + (size_t)11 * NN,
                                                       out + (size_t)k * NN * 3, predsc);
        if (k < 5) {
            gather3_csr<<<(NN + 3) / 4, 256, 0, stream>>>(E1, rowptr, dinv, predsc, xaggH16);
        }
    }
}